// Round 2
// baseline (282.605 us; speedup 1.0000x reference)
//
#include <hip/hip_runtime.h>

// Segment-mean over a sorted ragged batch.
//   x:            [N, D] float32   (N = 1e6, D = 256)
//   segment_ids:  [N]    int32, SORTED ascending in [0, B)
//   out:          [B, D] float32   (B = 16)
//
// Memory-bound: 1.028 GB read -> ~163 us floor at 6.3 TB/s.
//
// Key structural fact: ids are sorted and B=16, so there are only 15
// transition rows in the whole input. A block whose chunk endpoints share
// a segment id (~2033 of 2048 blocks) can stream its chunk with ZERO
// per-row id loads and no branches -> branch-free unrolled float4
// accumulation (4 KiB in flight per wave per iteration). Only blocks
// containing a transition (<=15) take the per-row path.

constexpr int D = 256;   // feature dim
constexpr int B = 16;    // number of segments

__global__ void zero_ws_kernel(float* __restrict__ ws, int n) {
    int i = blockIdx.x * blockDim.x + threadIdx.x;
    if (i < n) ws[i] = 0.0f;
}

__device__ __forceinline__ void flush_acc(int cur, const float4& acc, int cnt,
                                          int lane, float* __restrict__ sums,
                                          float* __restrict__ counts) {
    if (cur < 0 || cnt == 0) return;
    float* p = sums + cur * D + lane * 4;
    atomicAdd(p + 0, acc.x);
    atomicAdd(p + 1, acc.y);
    atomicAdd(p + 2, acc.z);
    atomicAdd(p + 3, acc.w);
    if (lane == 0) atomicAdd(counts + cur, (float)cnt);
}

__global__ __launch_bounds__(256) void seg_sum_kernel(
        const float4* __restrict__ x, const int* __restrict__ seg,
        float* __restrict__ sums, float* __restrict__ counts, int N) {
    const int lane = threadIdx.x & 63;   // owns features [lane*4, lane*4+4)
    const int wave = threadIdx.x >> 6;   // 4 waves/block, one row each per iter

    const int rowsPerBlock = (N + gridDim.x - 1) / gridDim.x;
    const int r0 = blockIdx.x * rowsPerBlock;
    const int r1 = min(N, r0 + rowsPerBlock);
    if (r0 >= r1) return;

    const int sFirst = seg[r0];
    const int sLast  = seg[r1 - 1];

    if (sFirst == sLast) {
        // ---- fast path: whole chunk is one segment (no per-row id loads) ----
        float4 a0 = make_float4(0.f, 0.f, 0.f, 0.f);
        float4 a1 = make_float4(0.f, 0.f, 0.f, 0.f);
        float4 a2 = make_float4(0.f, 0.f, 0.f, 0.f);
        float4 a3 = make_float4(0.f, 0.f, 0.f, 0.f);
        int cnt = 0;
        int r = r0 + wave;
        // 4-row unroll per wave (stride 16 = 4 waves * 4 rows) -> 4 KiB of
        // independent loads in flight per wave per iteration.
        for (; r + 12 < r1; r += 16) {
            float4 v0 = x[(size_t)r        * (D / 4) + lane];
            float4 v1 = x[(size_t)(r + 4)  * (D / 4) + lane];
            float4 v2 = x[(size_t)(r + 8)  * (D / 4) + lane];
            float4 v3 = x[(size_t)(r + 12) * (D / 4) + lane];
            a0.x += v0.x; a0.y += v0.y; a0.z += v0.z; a0.w += v0.w;
            a1.x += v1.x; a1.y += v1.y; a1.z += v1.z; a1.w += v1.w;
            a2.x += v2.x; a2.y += v2.y; a2.z += v2.z; a2.w += v2.w;
            a3.x += v3.x; a3.y += v3.y; a3.z += v3.z; a3.w += v3.w;
            cnt += 4;
        }
        for (; r < r1; r += 4) {
            float4 v = x[(size_t)r * (D / 4) + lane];
            a0.x += v.x; a0.y += v.y; a0.z += v.z; a0.w += v.w;
            ++cnt;
        }
        a0.x += a1.x + a2.x + a3.x;
        a0.y += a1.y + a2.y + a3.y;
        a0.z += a1.z + a2.z + a3.z;
        a0.w += a1.w + a2.w + a3.w;
        flush_acc(sFirst, a0, cnt, lane, sums, counts);
    } else {
        // ---- slow path: chunk contains >=1 transition (<=15 blocks) ----
        float4 acc = make_float4(0.f, 0.f, 0.f, 0.f);
        int cur = -1;
        int cnt = 0;
        for (int r = r0 + wave; r < r1; r += 4) {
            int s = seg[r];  // wave-uniform load
            float4 v = x[(size_t)r * (D / 4) + lane];
            if (s != cur) {  // uniform branch, fires a handful of times
                flush_acc(cur, acc, cnt, lane, sums, counts);
                acc = make_float4(0.f, 0.f, 0.f, 0.f);
                cnt = 0;
                cur = s;
            }
            acc.x += v.x; acc.y += v.y; acc.z += v.z; acc.w += v.w;
            ++cnt;
        }
        flush_acc(cur, acc, cnt, lane, sums, counts);
    }
}

__global__ void finalize_kernel(const float* __restrict__ sums,
                                const float* __restrict__ counts,
                                float* __restrict__ out) {
    int i = blockIdx.x * blockDim.x + threadIdx.x;
    if (i < B * D) {
        int b = i >> 8;  // i / D (D == 256)
        out[i] = sums[i] / fmaxf(counts[b], 1.0f);
    }
}

extern "C" void kernel_launch(void* const* d_in, const int* in_sizes, int n_in,
                              void* d_out, int out_size, void* d_ws, size_t ws_size,
                              hipStream_t stream) {
    const float4* x  = (const float4*)d_in[0];      // [N, D] fp32
    const int*   seg = (const int*)d_in[1];         // [N] int32, sorted
    float*       out = (float*)d_out;               // [B, D] fp32

    const int N = in_sizes[1];                      // 1e6 rows

    // Workspace accumulators: sums [B*D] then counts [B]. Zeroed every call
    // (harness poisons once, never re-poisons between replays).
    float* sums   = (float*)d_ws;
    float* counts = sums + B * D;
    const int nws = B * D + B;
    zero_ws_kernel<<<(nws + 255) / 256, 256, 0, stream>>>(sums, nws);

    // 2048 blocks x 4 waves = 8192 waves = 32 waves/CU (max occupancy) for
    // latency hiding; atomic flush traffic stays ~2M adds over 16 KB (L2).
    const int blocks = 2048;
    seg_sum_kernel<<<blocks, 256, 0, stream>>>(x, seg, sums, counts, N);

    finalize_kernel<<<(B * D + 255) / 256, 256, 0, stream>>>(sums, counts, out);
}

// Round 3
// 230.114 us; speedup vs baseline: 1.2281x; 1.2281x over previous
//
#include <hip/hip_runtime.h>

// Segment-mean over a sorted ragged batch.
//   x:            [N, D] float32   (N = 1e6, D = 256)
//   segment_ids:  [N]    int32, SORTED ascending in [0, B)
//   out:          [B, D] float32   (B = 16)
//
// Memory-bound: 1.028 GB read -> ~163 us floor at 6.3 TB/s.
//
// R2 lesson: the atomic flush tail is the secondary bottleneck — every
// wave flushing 257 atomicAdds into a 16 KB region serializes per cache
// line at L2. This version flushes ONCE PER BLOCK (LDS-combine the 4 wave
// accumulators first), cutting atomics 4x vs R1, and keeps the R2
// streaming fast path (sorted ids + B=16 => only 15 transition rows; ~all
// blocks are single-segment and need zero per-row id loads).

constexpr int D = 256;   // feature dim
constexpr int B = 16;    // number of segments

__global__ void zero_ws_kernel(float* __restrict__ ws, int n) {
    int i = blockIdx.x * blockDim.x + threadIdx.x;
    if (i < n) ws[i] = 0.0f;
}

__device__ __forceinline__ void flush_acc_wave(int cur, const float4& acc, int cnt,
                                               int lane, float* __restrict__ sums,
                                               float* __restrict__ counts) {
    if (cur < 0 || cnt == 0) return;
    float* p = sums + cur * D + lane * 4;
    atomicAdd(p + 0, acc.x);
    atomicAdd(p + 1, acc.y);
    atomicAdd(p + 2, acc.z);
    atomicAdd(p + 3, acc.w);
    if (lane == 0) atomicAdd(counts + cur, (float)cnt);
}

__global__ __launch_bounds__(256) void seg_sum_kernel(
        const float4* __restrict__ x, const int* __restrict__ seg,
        float* __restrict__ sums, float* __restrict__ counts, int N) {
    const int lane = threadIdx.x & 63;   // owns features [lane*4, lane*4+4)
    const int wave = threadIdx.x >> 6;   // 4 waves/block

    __shared__ float4 lds_acc[4][64];    // per-wave lane accumulators
    __shared__ int    lds_cnt[4];        // per-wave row counts

    const int rowsPerBlock = (N + gridDim.x - 1) / gridDim.x;
    const int r0 = blockIdx.x * rowsPerBlock;
    const int r1 = min(N, r0 + rowsPerBlock);
    if (r0 >= r1) return;

    const int sFirst = seg[r0];
    const int sLast  = seg[r1 - 1];

    if (sFirst == sLast) {
        // ---- fast path: whole chunk is one segment (no per-row id loads) ----
        float4 a0 = make_float4(0.f, 0.f, 0.f, 0.f);
        float4 a1 = make_float4(0.f, 0.f, 0.f, 0.f);
        float4 a2 = make_float4(0.f, 0.f, 0.f, 0.f);
        float4 a3 = make_float4(0.f, 0.f, 0.f, 0.f);
        int cnt = 0;
        int r = r0 + wave;
        // 4-row unroll per wave (stride 16 = 4 waves * 4 rows): 4 KiB of
        // independent loads in flight per wave per iteration.
        for (; r + 12 < r1; r += 16) {
            float4 v0 = x[(size_t)r        * (D / 4) + lane];
            float4 v1 = x[(size_t)(r + 4)  * (D / 4) + lane];
            float4 v2 = x[(size_t)(r + 8)  * (D / 4) + lane];
            float4 v3 = x[(size_t)(r + 12) * (D / 4) + lane];
            a0.x += v0.x; a0.y += v0.y; a0.z += v0.z; a0.w += v0.w;
            a1.x += v1.x; a1.y += v1.y; a1.z += v1.z; a1.w += v1.w;
            a2.x += v2.x; a2.y += v2.y; a2.z += v2.z; a2.w += v2.w;
            a3.x += v3.x; a3.y += v3.y; a3.z += v3.z; a3.w += v3.w;
            cnt += 4;
        }
        for (; r < r1; r += 4) {
            float4 v = x[(size_t)r * (D / 4) + lane];
            a0.x += v.x; a0.y += v.y; a0.z += v.z; a0.w += v.w;
            ++cnt;
        }
        a0.x += a1.x + a2.x + a3.x;
        a0.y += a1.y + a2.y + a3.y;
        a0.z += a1.z + a2.z + a3.z;
        a0.w += a1.w + a2.w + a3.w;

        // ---- block-level combine in LDS: ONE atomic flush per block ----
        lds_acc[wave][lane] = a0;
        if (lane == 0) lds_cnt[wave] = cnt;
        __syncthreads();
        // thread t owns feature t: sum across the 4 waves (conflict-free:
        // consecutive t -> consecutive banks).
        const int t = threadIdx.x;
        const float* lf = (const float*)lds_acc;  // [4][256] floats
        float s = lf[t] + lf[256 + t] + lf[512 + t] + lf[768 + t];
        atomicAdd(sums + sFirst * D + t, s);
        if (t == 0) {
            float c = (float)(lds_cnt[0] + lds_cnt[1] + lds_cnt[2] + lds_cnt[3]);
            atomicAdd(counts + sFirst, c);
        }
    } else {
        // ---- slow path: chunk contains >=1 transition (<=15 blocks) ----
        float4 acc = make_float4(0.f, 0.f, 0.f, 0.f);
        int cur = -1;
        int cnt = 0;
        for (int r = r0 + wave; r < r1; r += 4) {
            int s = seg[r];  // wave-uniform load
            float4 v = x[(size_t)r * (D / 4) + lane];
            if (s != cur) {  // uniform branch, fires a handful of times
                flush_acc_wave(cur, acc, cnt, lane, sums, counts);
                acc = make_float4(0.f, 0.f, 0.f, 0.f);
                cnt = 0;
                cur = s;
            }
            acc.x += v.x; acc.y += v.y; acc.z += v.z; acc.w += v.w;
            ++cnt;
        }
        flush_acc_wave(cur, acc, cnt, lane, sums, counts);
    }
}

__global__ void finalize_kernel(const float* __restrict__ sums,
                                const float* __restrict__ counts,
                                float* __restrict__ out) {
    int i = blockIdx.x * blockDim.x + threadIdx.x;
    if (i < B * D) {
        int b = i >> 8;  // i / D (D == 256)
        out[i] = sums[i] / fmaxf(counts[b], 1.0f);
    }
}

extern "C" void kernel_launch(void* const* d_in, const int* in_sizes, int n_in,
                              void* d_out, int out_size, void* d_ws, size_t ws_size,
                              hipStream_t stream) {
    const float4* x  = (const float4*)d_in[0];      // [N, D] fp32
    const int*   seg = (const int*)d_in[1];         // [N] int32, sorted
    float*       out = (float*)d_out;               // [B, D] fp32

    const int N = in_sizes[1];                      // 1e6 rows

    // Workspace accumulators: sums [B*D] then counts [B]. Zeroed every call
    // (harness poisons once, never re-poisons between replays).
    float* sums   = (float*)d_ws;
    float* counts = sums + B * D;
    const int nws = B * D + B;
    zero_ws_kernel<<<(nws + 255) / 256, 256, 0, stream>>>(sums, nws);

    // 1024 blocks (R1 known-good grid): 16 waves/CU, ~977 rows/block.
    // Atomic flushes: ~1024 * 257 ~= 265K (4x fewer than R1, 8x vs R2).
    const int blocks = 1024;
    seg_sum_kernel<<<blocks, 256, 0, stream>>>(x, seg, sums, counts, N);

    finalize_kernel<<<(B * D + 255) / 256, 256, 0, stream>>>(sums, counts, out);
}